// Round 9
// baseline (145.260 us; speedup 1.0000x reference)
//
#include <hip/hip_runtime.h>
#include <hip/hip_fp8.h>

#define P 196
#define NN 32
#define MARGIN 0.5f
#define NCH 12            // K-chunks of 64 int8 elements
#define APIECES 896       // A: 224 rows * 4 pieces (16 B) per chunk
#define BPIECES 448       // B q-half: 112 rows * 4 pieces
#define CHB (APIECES * 16)             // 14336 bytes per image-chunk
#define ABUF CHB                       // one A-only LDS buffer

#define QS 400.0f                      // int8 quant scale: x_int = round(x*QS)
#define INV_QS2 (1.0f / (QS * QS))     // sim = int_dot * INV_QS2

typedef int   intx4   __attribute__((ext_vector_type(4)));   // 16 B = one K=64 i8 frag
typedef float floatx4 __attribute__((ext_vector_type(4)));

typedef __attribute__((address_space(1))) const unsigned char g_u8;
typedef __attribute__((address_space(3))) unsigned char l_u8;

// Workspace Y layout (int8 symmetric-quant, chunk-major, swizzled) — geometry
// identical to the HW-verified R8/R16 layout: chunk c covers k=c*64..c*64+63;
// piece(img,c,r,kg') = 16 B at (img*12+c)*14336+(r*4+kg')*16, kg'=kg^((r>>1)&3).
// One piece = one 4-VGPR operand of mfma_i32_16x16x64_i8. A/B share the same
// (lane,byte)->k permutation; the dot is permutation-invariant (validated
// R11/R16, absmax 0).

// ---------------------------------------------------------------------------
// Kernel 1 (unchanged from R16, verified): normalize + int8 quantize.
// ---------------------------------------------------------------------------
__global__ __launch_bounds__(512) void norm_kernel(const float* __restrict__ nrm,
                                                   const float* __restrict__ dft,
                                                   unsigned char* __restrict__ Y,
                                                   float* __restrict__ out) {
    if (blockIdx.x == 0 && threadIdx.x == 0) out[0] = 0.0f;
    __shared__ uint2 rowbuf[8][100];             // 96 groups of 8 bytes per row

    int img  = blockIdx.x / 28;
    int rg   = blockIdx.x % 28;
    int wave = threadIdx.x >> 6;
    int lane = threadIdx.x & 63;
    int p = rg * 8 + wave;

    if (p < P) {
        const float* src = (img < NN) ? nrm + ((size_t)img * P + p) * 768
                                      : dft + ((size_t)(img - NN) * P + p) * 768;
        float4 a0 = *(const float4*)(src + lane * 8);
        float4 a1 = *(const float4*)(src + lane * 8 + 4);
        float4 b0 = {0,0,0,0}, b1 = {0,0,0,0};
        float ss = a0.x*a0.x + a0.y*a0.y + a0.z*a0.z + a0.w*a0.w
                 + a1.x*a1.x + a1.y*a1.y + a1.z*a1.z + a1.w*a1.w;
        if (lane < 32) {
            b0 = *(const float4*)(src + 512 + lane * 8);
            b1 = *(const float4*)(src + 512 + lane * 8 + 4);
            ss += b0.x*b0.x + b0.y*b0.y + b0.z*b0.z + b0.w*b0.w
                + b1.x*b1.x + b1.y*b1.y + b1.z*b1.z + b1.w*b1.w;
        }
        #pragma unroll
        for (int o = 32; o > 0; o >>= 1) ss += __shfl_xor(ss, o);
        float qsc = QS / (sqrtf(ss) + 1e-8f);    // normalize * quant scale

        auto qi = [&](float f) -> unsigned {     // fp32 -> clamped int8 byte
            float v = f * qsc;
            v = fminf(fmaxf(v, -127.0f), 127.0f);
            return (unsigned)((int)rintf(v) & 255);
        };
        auto pack8 = [&](float4 x0, float4 x1) {
            uint2 g;
            g.x = qi(x0.x) | (qi(x0.y) << 8) | (qi(x0.z) << 16) | (qi(x0.w) << 24);
            g.y = qi(x1.x) | (qi(x1.y) << 8) | (qi(x1.z) << 16) | (qi(x1.w) << 24);
            return g;
        };
        rowbuf[wave][lane] = pack8(a0, a1);                     // groups 0..63
        if (lane < 32) rowbuf[wave][64 + lane] = pack8(b0, b1); // groups 64..95
    }
    __syncthreads();

    int idx = threadIdx.x;
    if (idx < 384) {
        int c = idx >> 5, r = (idx >> 2) & 7, kgp = idx & 3;
        int pr = rg * 8 + r;
        if (pr < P) {
            int kg = kgp ^ ((pr >> 1) & 3);
            uint2 lo = rowbuf[r][c * 8 + kg];        // k-low half
            uint2 hi = rowbuf[r][c * 8 + 4 + kg];    // k-high half
            uint4 o; o.x = lo.x; o.y = lo.y; o.z = hi.x; o.w = hi.y;
            *(uint4*)(Y + (size_t)(img * NCH + c) * CHB + (pr * 4 + kgp) * 16) = o;
        }
    }
}

// ---------------------------------------------------------------------------
// Pair ordering table (compile-time): macro-tiled for L2 locality (R10,
// verified: FETCH 33 -> 25.7 MB). v[b] = ia | (ja<<8), ja global index.
// ---------------------------------------------------------------------------
struct PairTab { unsigned short v[1520]; };
static constexpr PairTab mk_tab() {
    PairTab t{};
    int n = 0;
    for (int gi = 0; gi < 4; ++gi)                  // nn: 496 pairs, i<j
        for (int gj = gi; gj < 4; ++gj)
            for (int i = gi*8; i < gi*8 + 8; ++i) {
                int j0 = (gi == gj) ? i + 1 : gj*8;
                for (int j = j0; j < gj*8 + 8; ++j)
                    t.v[n++] = (unsigned short)(i | (j << 8));
            }
    for (int gi = 0; gi < 4; ++gi)                  // nd: 1024 pairs
        for (int gd = 0; gd < 4; ++gd)
            for (int i = gi*8; i < gi*8 + 8; ++i)
                for (int d = gd*8; d < gd*8 + 8; ++d)
                    t.v[n++] = (unsigned short)(i | ((32 + d) << 8));
    return t;
}
__constant__ PairTab PTAB = mk_tab();

// ---------------------------------------------------------------------------
// Kernel 2 (R17): B OPERANDS GLOBAL->VGPR (off the LDS pipe).
//   R16 analysis: LDS data path = (59 reads + 21 DMA-writes)*1KB per
//   block-phase ~= 117k cyc/CU = 73% of wall — the saturated pipe. Each wave
//   needs only BC (2-3) B-frags/chunk and the B piece address is exactly the
//   same (r16*4+sw)*16 arithmetic in GLOBAL Y (coalesced 1024 B/frag, L2-hot
//   via macro-tiling). So: LDS stages A ONLY (14 DMAs/chunk); B is loaded
//   direct to a double-banked register set one phase ahead.
//   LDS per block-phase: 59+21 -> 39+14 pieces; B's 20 KB/phase moves to the
//   underused VMEM/L2 path. Correctness is reorder-robust: A-DMA uses my
//   counted vmcnt over my intrinsics (any compiler interleave only deepens
//   the drain); B-reg deps are compiler-tracked (its own waitcnt insertion).
//   Regs: ~70 arch + 48 acc < 128 cap (512,4). LDS: 3 x 14336 = 43008 B.
// Rects, swizzle, i8 MFMA, epilogue identical to R16 (single variable).
// ---------------------------------------------------------------------------
__device__ constexpr int WAS[8] = {0, 0, 7, 7,  4, 7, 10, 0};   // A start
__device__ constexpr int WAC[8] = {7, 7, 6, 6,  3, 3,  3, 4};   // A count
__device__ constexpr int WBS[8] = {0, 2, 0, 2,  4, 4,  4, 4};   // B start
__device__ constexpr int WBC[8] = {2, 2, 2, 2,  3, 3,  3, 3};   // B count

template<int W>
__device__ void wave_worker(uint4* tiles, const unsigned char* gA,
                            const unsigned char* gB, int lane) {
    constexpr int AS = WAS[W], AC = WAC[W], BS = WBS[W], BC = WBC[W];
    constexpr int DA = (W < 6) ? 2 : 1;   // own A-DMAs per chunk (i = W+8u < 14)

    int r16  = lane & 15;
    int quad = lane >> 4;                 // 0..3 : k-group of 8
    int sw   = quad ^ ((r16 >> 1) & 3);   // XOR swizzle (verified conflict-free)
    int fofs = (r16 * 4 + sw) * 16;       // per-lane frag byte offset
    l_u8* lds0 = (l_u8*)tiles;

    intx4 acc[AC][BC];
    #pragma unroll
    for (int a = 0; a < AC; ++a)
        #pragma unroll
        for (int b = 0; b < BC; ++b)
            acc[a][b] = (intx4){0, 0, 0, 0};

    intx4 bk0[BC], bk1[BC];               // B double banks (even/odd chunk)

    // 14 A-DMAs/chunk over 8 waves: wave W issues i = W (+ W+8 if < 14)
    auto stageA = [&](const unsigned char* ga, l_u8* ldsb) {
        #pragma unroll
        for (int u = 0; u < 2; ++u) {
            if (W + 8 * u < 14) {
                int i = W + 8 * u;
                __builtin_amdgcn_global_load_lds((const g_u8*)(ga + (i * 64 + lane) * 16),
                                                 ldsb + i * 1024, 16, 0, 0);
            }
        }
    };
    // B frags for this wave's cols, straight from Y (coalesced, L2-hot)
    auto loadB = [&](const unsigned char* gbc, intx4* bk) {
        #pragma unroll
        for (int b = 0; b < BC; ++b)
            bk[b] = *(const intx4*)(gbc + (BS + b) * 1024 + fofs);
    };
    auto burst = [&](const intx4* afr, const intx4* bk) {
        __builtin_amdgcn_s_setprio(1);
        #pragma unroll
        for (int a = 0; a < AC; ++a)
            #pragma unroll
            for (int b = 0; b < BC; ++b)
                acc[a][b] = __builtin_amdgcn_mfma_i32_16x16x64_i8(
                    afr[a], bk[b], acc[a][b], 0, 0, 0);
        __builtin_amdgcn_s_setprio(0);
    };

    // prologue (issue order matters for the counted drain):
    stageA(gA, lds0);                    // A(0) -> buf0   [DA]
    loadB(gB, bk0);                      // B(0) -> bank0  [BC]
    stageA(gA + CHB, lds0 + ABUF);       // A(1) -> buf1   [DA]
    const unsigned char* gAn = gA + 2 * CHB;   // next A chunk to stage
    const unsigned char* gBn = gB + CHB;       // next B chunk to load

    const char* rb0 = (const char*)tiles;        // buffer of chunk cb
    const char* rb1 = rb0 + ABUF;                // chunk cb+1
    const char* rb2 = rb1 + ABUF;                // stage target (cb+2)

    for (int cb = 0; cb < NCH; cb += 2) {
        {   // even phase c = cb: MFMA bank0, prefetch B(c+1)->bank1
            int c = cb;
            if (c == NCH - 1) __builtin_amdgcn_s_waitcnt(0xF70);       // vmcnt(0)
            else              __builtin_amdgcn_s_waitcnt(0xF70 | DA);  // vmcnt(DA)
            __builtin_amdgcn_s_barrier();
            __builtin_amdgcn_sched_barrier(0);   // no ds_read above barrier
            intx4 afr[AC];
            #pragma unroll
            for (int a = 0; a < AC; ++a)
                afr[a] = *(const intx4*)(rb0 + fofs + (AS + a) * 1024);
            if (c + 1 < NCH) { loadB(gBn, bk1); gBn += CHB; }
            if (c + 2 < NCH) { stageA(gAn, (l_u8*)rb2); gAn += CHB; }
            __builtin_amdgcn_sched_barrier(0);   // issues stay above the MFMAs
            burst(afr, bk0);
        }
        {   // odd phase c = cb+1: MFMA bank1, prefetch B(c+1)->bank0
            int c = cb + 1;
            if (c == NCH - 1) __builtin_amdgcn_s_waitcnt(0xF70);
            else              __builtin_amdgcn_s_waitcnt(0xF70 | DA);
            __builtin_amdgcn_s_barrier();
            __builtin_amdgcn_sched_barrier(0);
            intx4 afr[AC];
            #pragma unroll
            for (int a = 0; a < AC; ++a)
                afr[a] = *(const intx4*)(rb1 + fofs + (AS + a) * 1024);
            if (c + 1 < NCH) { loadB(gBn, bk0); gBn += CHB; }
            if (c + 2 < NCH) { stageA(gAn, (l_u8*)rb0); gAn += CHB; }
            __builtin_amdgcn_sched_barrier(0);
            burst(afr, bk1);
        }
        // rotate buffers: {rb0,rb1,rb2} <- {rb2,rb0,rb1}
        const char* t = rb0; rb0 = rb2; rb2 = rb1; rb1 = t;
    }

    __syncthreads();                 // all waves' A reads done; alias LDS
    float* colmaxrow = (float*)tiles + W * 112;

    // C/D: col q = lane&15, row p = (AS+a)*16 + quad*4 + r (shape-determined).
    #pragma unroll
    for (int b = 0; b < BC; ++b) {
        int m = (int)0x80000000;
        #pragma unroll
        for (int a = 0; a < AC; ++a) {
            int pbase = (AS + a) * 16 + quad * 4;
            #pragma unroll
            for (int r = 0; r < 4; ++r)
                if (pbase + r < P) m = max(m, acc[a][b][r]);
        }
        m = max(m, __shfl_xor(m, 16));
        m = max(m, __shfl_xor(m, 32));
        if (quad == 0) colmaxrow[(BS + b) * 16 + r16] = (float)m * INV_QS2;
    }
    // non-owned columns: neutral element (stale LDS would alias tile data)
    #pragma unroll
    for (int t = 0; t < 7; ++t)
        if (t < BS || t >= BS + BC)
            if (quad == 0) colmaxrow[t * 16 + r16] = -3.0e38f;
}

__global__ __launch_bounds__(512, 4) void pair_kernel(const unsigned char* __restrict__ Y,
                                                      float* __restrict__ out) {
    __shared__ uint4 tiles[3 * APIECES];   // 43008 B, A-only (colmax aliased)
    __shared__ float redp[8];

    int bx = blockIdx.x;
    int l  = (bx & 7) * 380 + (bx >> 3);   // XCD k owns logical [380k, 380k+380)
    int b  = l >> 1;                 // pair index (macro-tiled order)
    int qh = l & 1;                  // q-half
    unsigned short pk = PTAB.v[b];
    int ia = pk & 255;
    int ja = pk >> 8;
    bool is_nn = b < 496;

    int tid  = threadIdx.x;
    int lane = tid & 63;
    int wave = tid >> 6;             // 0..7

    const unsigned char* gA = Y + (size_t)ia * (NCH * CHB);
    const unsigned char* gB = Y + (size_t)ja * (NCH * CHB) + qh * (BPIECES * 16);

    switch (wave) {
        case 0: wave_worker<0>(tiles, gA, gB, lane); break;
        case 1: wave_worker<1>(tiles, gA, gB, lane); break;
        case 2: wave_worker<2>(tiles, gA, gB, lane); break;
        case 3: wave_worker<3>(tiles, gA, gB, lane); break;
        case 4: wave_worker<4>(tiles, gA, gB, lane); break;
        case 5: wave_worker<5>(tiles, gA, gB, lane); break;
        case 6: wave_worker<6>(tiles, gA, gB, lane); break;
        default: wave_worker<7>(tiles, gA, gB, lane); break;
    }

    __syncthreads();                 // all colmax rows written
    float* colmax = (float*)tiles;   // [8][112]

    float contrib = 0.f;
    if (tid < 112 && qh * 112 + tid < P) {       // q >= 196 are pad cols
        float cm = colmax[tid];
        #pragma unroll
        for (int w = 1; w < 8; ++w) cm = fmaxf(cm, colmax[w * 112 + tid]);
        contrib = is_nn ? (1.0f - cm) * (1.0f / (496.0f * 196.0f))
                        : fmaxf(cm - MARGIN, 0.0f) * (1.0f / (1024.0f * 196.0f));
    }
    #pragma unroll
    for (int o = 32; o > 0; o >>= 1) contrib += __shfl_down(contrib, o);
    if (lane == 0) redp[wave] = contrib;
    __syncthreads();
    if (tid == 0) {
        float s = redp[0] + redp[1] + redp[2] + redp[3]
                + redp[4] + redp[5] + redp[6] + redp[7];
        atomicAdd(out, s);
    }
}

// ---------------------------------------------------------------------------
extern "C" void kernel_launch(void* const* d_in, const int* in_sizes, int n_in,
                              void* d_out, int out_size, void* d_ws, size_t ws_size,
                              hipStream_t stream) {
    const float* nrm = (const float*)d_in[0];   // [32,196,768] fp32
    const float* dft = (const float*)d_in[1];   // [32,196,768] fp32
    float* out = (float*)d_out;                 // scalar fp32
    unsigned char* Y = (unsigned char*)d_ws;    // int8, 10.5 MB

    norm_kernel<<<64 * 28, 512, 0, stream>>>(nrm, dft, Y, out);
    pair_kernel<<<2 * (496 + 1024), 512, 0, stream>>>(Y, out);
}